// Round 1
// baseline (198.040 us; speedup 1.0000x reference)
//
#include <hip/hip_runtime.h>
#include <math.h>

#define NFFT 4096
#define LOG2N 12
#define HALF 2048
#define LSEG 2048   // L
#define SSZ 4096    // STATE_SIZE

static __device__ __forceinline__ double sigm_f32(float v) {
    // mimic reference: fp32 sigmoid then promote to f64
    return (double)(1.0f / (1.0f + expf(-v)));
}

static __device__ void inv4(const double a[4][4], double out[4][4]) {
    double m[4][8];
    for (int i = 0; i < 4; ++i) {
        for (int j = 0; j < 4; ++j) { m[i][j] = a[i][j]; m[i][j + 4] = (i == j) ? 1.0 : 0.0; }
    }
    for (int c = 0; c < 4; ++c) {
        int piv = c; double best = fabs(m[c][c]);
        for (int r = c + 1; r < 4; ++r) { double v = fabs(m[r][c]); if (v > best) { best = v; piv = r; } }
        if (piv != c) for (int j = 0; j < 8; ++j) { double t = m[c][j]; m[c][j] = m[piv][j]; m[piv][j] = t; }
        double d = 1.0 / m[c][c];
        for (int j = 0; j < 8; ++j) m[c][j] *= d;
        for (int r = 0; r < 4; ++r) {
            if (r == c) continue;
            double f = m[r][c];
            for (int j = 0; j < 8; ++j) m[r][j] -= f * m[c][j];
        }
    }
    for (int i = 0; i < 4; ++i) for (int j = 0; j < 4; ++j) out[i][j] = m[i][j + 4];
}

// Per-batch filter coefficients: num = [n0,n1,n2], den = [1,d1,d2]
__global__ void preamp_coef_kernel(const float* __restrict__ cond,
                                   const float* __restrict__ a_rg,
                                   const float* __restrict__ a_r1,
                                   const float* __restrict__ a_c1,
                                   const float* __restrict__ a_c2,
                                   const float* __restrict__ cond_w,
                                   const float* __restrict__ cond_b,
                                   double* __restrict__ coef, int B) {
    int b = blockIdx.x * blockDim.x + threadIdx.x;
    if (b >= B) return;

    const double T = 1.0 / 44100.0;
    const double RG = (0.9 + sigm_f32(a_rg[0]) * 0.2) * 1.0e6;
    const double R1 = (0.99 + sigm_f32(a_r1[0]) * 0.02) * 4.7e5;
    const double C1 = (0.9 + sigm_f32(a_c1[0]) * 0.2) * 3.3e-9;
    const double C2 = (0.9 + sigm_f32(a_c2[0]) * 0.2) * 1.0e-9;
    const double g1 = 1.0 / R1;
    const double gc1 = 2.0 * C1 / T;
    const double gc2 = 2.0 * C2 / T;

    // p in fp32 exactly like reference, then promote
    float zf = cond[b] * cond_w[0] + cond_b[0];
    float pot = 1.0f / (1.0f + expf(-zf));
    float pr = (powf(10.0f, pot) - 1.0f) / 9.0f;
    pr = fminf(fmaxf(pr, 1e-4f), 1.0f - 1e-4f);
    double p = (double)pr;

    double So[4][4] = {
        { gc1,     -gc1,      0.0, 1.0},
        {-gc1,      gc1 + g1, 0.0, 0.0},
        { 0.0,      0.0,      gc2, 0.0},
        { 1.0,      0.0,      0.0, 0.0}};
    double S[4][4];
    inv4(So, S);

    // Quadratic forms with v0=[0,1,-1,0], v1=[0,0,1,0], x0=[1,-1,0,0], x1=[0,0,1,0], o=[0,0,1,0], u=e3
    double Q00 = S[1][1] - S[1][2] - S[2][1] + S[2][2];
    double Q01 = S[1][2] - S[2][2];
    double Q10 = S[2][1] - S[2][2];
    double Q11 = S[2][2];

    double Ux00 = S[0][1] - S[0][2] - S[1][1] + S[1][2];
    double Ux01 = S[0][2] - S[1][2];
    double Ux10 = S[2][1] - S[2][2];
    double Ux11 = S[2][2];

    double Uo0 = S[2][1] - S[2][2], Uo1 = S[2][2];
    double Uu0 = S[3][1] - S[3][2], Uu1 = S[3][2];

    double P00 = S[0][0] - S[0][1] - S[1][0] + S[1][1];
    double P01 = S[0][2] - S[1][2];
    double P10 = S[2][0] - S[2][1];
    double P11 = S[2][2];

    double Ao00 = 2.0 * gc1 * P00 - 1.0, Ao01 = 2.0 * gc1 * P01;
    double Ao10 = 2.0 * gc2 * P10,       Ao11 = 2.0 * gc2 * P11 - 1.0;

    double Bo0 = 2.0 * gc1 * (S[0][3] - S[1][3]);
    double Bo1 = 2.0 * gc2 * S[2][3];

    double Do0 = S[2][0] - S[2][1], Do1 = S[2][2];
    double Eo  = S[2][3];

    // ZGx @ Ux
    double T00 = 2.0 * gc1 * Ux00, T01 = 2.0 * gc1 * Ux01;
    double T10 = 2.0 * gc2 * Ux10, T11 = 2.0 * gc2 * Ux11;

    // RvQ = inv(diag(d) + Q)
    double d0 = (1.0 - p) * RG, d1v = p * RG;
    double M00 = d0 + Q00, M01 = Q01, M10 = Q10, M11 = d1v + Q11;
    double idet = 1.0 / (M00 * M11 - M01 * M10);
    double G00 =  M11 * idet, G01 = -M01 * idet;
    double G10 = -M10 * idet, G11 =  M00 * idet;

    double TG00 = T00 * G00 + T01 * G10, TG01 = T00 * G01 + T01 * G11;
    double TG10 = T10 * G00 + T11 * G10, TG11 = T10 * G01 + T11 * G11;

    // A = Ao - TG @ Ux^T
    double A00 = Ao00 - (TG00 * Ux00 + TG01 * Ux01);
    double A01 = Ao01 - (TG00 * Ux10 + TG01 * Ux11);
    double A10 = Ao10 - (TG10 * Ux00 + TG11 * Ux01);
    double A11 = Ao11 - (TG10 * Ux10 + TG11 * Ux11);

    double Bm0 = Bo0 - (TG00 * Uu0 + TG01 * Uu1);
    double Bm1 = Bo1 - (TG10 * Uu0 + TG11 * Uu1);

    double w0v = Uo0 * G00 + Uo1 * G10, w1v = Uo0 * G01 + Uo1 * G11;
    double Dm0 = Do0 - (w0v * Ux00 + w1v * Ux01);
    double Dm1 = Do1 - (w0v * Ux10 + w1v * Ux11);
    double Em  = Eo  - (w0v * Uu0 + w1v * Uu1);

    double den1 = -(A00 + A11);
    double den2 = A00 * A11 - A01 * A10;
    double Mm00 = A00 - Bm0 * Dm0, Mm01 = A01 - Bm0 * Dm1;
    double Mm10 = A10 - Bm1 * Dm0, Mm11 = A11 - Bm1 * Dm1;
    double num0 = Em;
    double num1 = -(Mm00 + Mm11) + (Em - 1.0) * den1;
    double num2 = (Mm00 * Mm11 - Mm01 * Mm10) + (Em - 1.0) * den2;

    coef[(size_t)b * 5 + 0] = num0;
    coef[(size_t)b * 5 + 1] = num1;
    coef[(size_t)b * 5 + 2] = num2;
    coef[(size_t)b * 5 + 3] = den1;
    coef[(size_t)b * 5 + 4] = den2;
}

// One block per batch: load [state tail | x] -> fwd FFT (DIF, nat->bitrev) ->
// multiply by H(z_k) at k=rev(j) -> inv FFT (DIT, bitrev->nat) -> write last 2048.
__global__ __launch_bounds__(256)
void preamp_fft_kernel(const float* __restrict__ x,
                       const float* __restrict__ state,
                       const double* __restrict__ coef,
                       float* __restrict__ out) {
    __shared__ float2 a_s[NFFT];     // 32 KB
    __shared__ float2 tw[HALF];      // 16 KB: tw[m] = (cos(2pi m/N), sin(2pi m/N))

    const int b = blockIdx.x;
    const int tid = threadIdx.x;

    const float* st = state + (size_t)b * SSZ + (SSZ - LSEG);
    const float* xb = x + (size_t)b * LSEG;

    for (int i = tid; i < NFFT; i += 256) {
        float v = (i < LSEG) ? st[i] : xb[i - LSEG];
        a_s[i] = make_float2(v, 0.0f);
    }
    const float w0 = (float)(2.0 * M_PI / (double)NFFT);
    for (int m = tid; m < HALF; m += 256) {
        float sn, cs;
        sincosf(w0 * (float)m, &sn, &cs);
        tw[m] = make_float2(cs, sn);
    }
    const double n0 = coef[(size_t)b * 5 + 0];
    const double n1 = coef[(size_t)b * 5 + 1];
    const double n2 = coef[(size_t)b * 5 + 2];
    const double dd1 = coef[(size_t)b * 5 + 3];
    const double dd2 = coef[(size_t)b * 5 + 4];
    __syncthreads();

    // forward DIF radix-2, twiddle exp(-i*2pi*j/(2*len))
    for (int s = LOG2N - 1; s >= 0; --s) {
        const int len = 1 << s;
        for (int t = tid; t < HALF; t += 256) {
            int j = t & (len - 1);
            int i0 = ((t >> s) << (s + 1)) + j;
            int i1 = i0 + len;
            float2 u = a_s[i0], v = a_s[i1];
            float dx = u.x - v.x, dy = u.y - v.y;
            float2 w = tw[j << (LOG2N - 1 - s)];
            a_s[i0] = make_float2(u.x + v.x, u.y + v.y);
            a_s[i1] = make_float2(dx * w.x + dy * w.y, dy * w.x - dx * w.y);
        }
        __syncthreads();
    }

    // pointwise: position j holds X[k], k = bitrev(j). Multiply by h(z_k), fp64.
    for (int j = tid; j < NFFT; j += 256) {
        unsigned k = __brev((unsigned)j) >> (32 - LOG2N);
        double zr, zi;
        if (k < HALF) { float2 t2 = tw[k];        zr =  (double)t2.x; zi = -(double)t2.y; }
        else          { float2 t2 = tw[k - HALF]; zr = -(double)t2.x; zi =  (double)t2.y; }
        double ar = n0 * zr + n1, ai = n0 * zi;
        double nr = ar * zr - ai * zi + n2, ni = ar * zi + ai * zr;
        double br = zr + dd1, bi = zi;
        double dr = br * zr - bi * zi + dd2, di = br * zi + bi * zr;
        double idn = 1.0 / (dr * dr + di * di);
        double hr = (nr * dr + ni * di) * idn;
        double hi = (ni * dr - nr * di) * idn;
        float2 X = a_s[j];
        double Xr = (double)X.x, Xi = (double)X.y;
        a_s[j] = make_float2((float)(Xr * hr - Xi * hi), (float)(Xr * hi + Xi * hr));
    }
    __syncthreads();

    // inverse DIT radix-2, twiddle exp(+i*2pi*j/(2*len)), input bitrev -> natural
    for (int s = 0; s < LOG2N; ++s) {
        const int len = 1 << s;
        for (int t = tid; t < HALF; t += 256) {
            int j = t & (len - 1);
            int i0 = ((t >> s) << (s + 1)) + j;
            int i1 = i0 + len;
            float2 w = tw[j << (LOG2N - 1 - s)];
            float2 v = a_s[i1];
            float tr = v.x * w.x - v.y * w.y;
            float ti = v.x * w.y + v.y * w.x;
            float2 u = a_s[i0];
            a_s[i0] = make_float2(u.x + tr, u.y + ti);
            a_s[i1] = make_float2(u.x - tr, u.y - ti);
        }
        __syncthreads();
    }

    const float scale = 1.0f / (float)NFFT;
    float* ob = out + (size_t)b * LSEG;
    for (int i = tid; i < LSEG; i += 256) {
        ob[i] = a_s[LSEG + i].x * scale;
    }
}

extern "C" void kernel_launch(void* const* d_in, const int* in_sizes, int n_in,
                              void* d_out, int out_size, void* d_ws, size_t ws_size,
                              hipStream_t stream) {
    const float* x     = (const float*)d_in[0];
    const float* cond  = (const float*)d_in[1];
    const float* state = (const float*)d_in[2];
    const float* a_rg  = (const float*)d_in[3];
    const float* a_r1  = (const float*)d_in[4];
    const float* a_c1  = (const float*)d_in[5];
    const float* a_c2  = (const float*)d_in[6];
    const float* c_w   = (const float*)d_in[7];
    const float* c_b   = (const float*)d_in[8];
    float* out = (float*)d_out;

    const int B = in_sizes[1];          // cond is [B,1]
    double* coef = (double*)d_ws;       // B*5 doubles

    preamp_coef_kernel<<<dim3((B + 255) / 256), dim3(256), 0, stream>>>(
        cond, a_rg, a_r1, a_c1, a_c2, c_w, c_b, coef, B);
    preamp_fft_kernel<<<dim3(B), dim3(256), 0, stream>>>(x, state, coef, out);
}

// Round 2
// 142.492 us; speedup vs baseline: 1.3898x; 1.3898x over previous
//
#include <hip/hip_runtime.h>
#include <math.h>

#define NFFT 4096
#define HALF 2048
#define LSEG 2048   // L
#define SSZ 4096    // STATE_SIZE

static __device__ __forceinline__ double sigm_f32(float v) {
    return (double)(1.0f / (1.0f + expf(-v)));
}

static __device__ void inv4(const double a[4][4], double out[4][4]) {
    double m[4][8];
    for (int i = 0; i < 4; ++i) {
        for (int j = 0; j < 4; ++j) { m[i][j] = a[i][j]; m[i][j + 4] = (i == j) ? 1.0 : 0.0; }
    }
    for (int c = 0; c < 4; ++c) {
        int piv = c; double best = fabs(m[c][c]);
        for (int r = c + 1; r < 4; ++r) { double v = fabs(m[r][c]); if (v > best) { best = v; piv = r; } }
        if (piv != c) for (int j = 0; j < 8; ++j) { double t = m[c][j]; m[c][j] = m[piv][j]; m[piv][j] = t; }
        double d = 1.0 / m[c][c];
        for (int j = 0; j < 8; ++j) m[c][j] *= d;
        for (int r = 0; r < 4; ++r) {
            if (r == c) continue;
            double f = m[r][c];
            for (int j = 0; j < 8; ++j) m[r][j] -= f * m[c][j];
        }
    }
    for (int i = 0; i < 4; ++i) for (int j = 0; j < 4; ++j) out[i][j] = m[i][j + 4];
}

__global__ void preamp_coef_kernel(const float* __restrict__ cond,
                                   const float* __restrict__ a_rg,
                                   const float* __restrict__ a_r1,
                                   const float* __restrict__ a_c1,
                                   const float* __restrict__ a_c2,
                                   const float* __restrict__ cond_w,
                                   const float* __restrict__ cond_b,
                                   double* __restrict__ coef, int B) {
    int b = blockIdx.x * blockDim.x + threadIdx.x;
    if (b >= B) return;

    const double T = 1.0 / 44100.0;
    const double RG = (0.9 + sigm_f32(a_rg[0]) * 0.2) * 1.0e6;
    const double R1 = (0.99 + sigm_f32(a_r1[0]) * 0.02) * 4.7e5;
    const double C1 = (0.9 + sigm_f32(a_c1[0]) * 0.2) * 3.3e-9;
    const double C2 = (0.9 + sigm_f32(a_c2[0]) * 0.2) * 1.0e-9;
    const double g1 = 1.0 / R1;
    const double gc1 = 2.0 * C1 / T;
    const double gc2 = 2.0 * C2 / T;

    float zf = cond[b] * cond_w[0] + cond_b[0];
    float pot = 1.0f / (1.0f + expf(-zf));
    float pr = (powf(10.0f, pot) - 1.0f) / 9.0f;
    pr = fminf(fmaxf(pr, 1e-4f), 1.0f - 1e-4f);
    double p = (double)pr;

    double So[4][4] = {
        { gc1,     -gc1,      0.0, 1.0},
        {-gc1,      gc1 + g1, 0.0, 0.0},
        { 0.0,      0.0,      gc2, 0.0},
        { 1.0,      0.0,      0.0, 0.0}};
    double S[4][4];
    inv4(So, S);

    double Q00 = S[1][1] - S[1][2] - S[2][1] + S[2][2];
    double Q01 = S[1][2] - S[2][2];
    double Q10 = S[2][1] - S[2][2];
    double Q11 = S[2][2];

    double Ux00 = S[0][1] - S[0][2] - S[1][1] + S[1][2];
    double Ux01 = S[0][2] - S[1][2];
    double Ux10 = S[2][1] - S[2][2];
    double Ux11 = S[2][2];

    double Uo0 = S[2][1] - S[2][2], Uo1 = S[2][2];
    double Uu0 = S[3][1] - S[3][2], Uu1 = S[3][2];

    double P00 = S[0][0] - S[0][1] - S[1][0] + S[1][1];
    double P01 = S[0][2] - S[1][2];
    double P10 = S[2][0] - S[2][1];
    double P11 = S[2][2];

    double Ao00 = 2.0 * gc1 * P00 - 1.0, Ao01 = 2.0 * gc1 * P01;
    double Ao10 = 2.0 * gc2 * P10,       Ao11 = 2.0 * gc2 * P11 - 1.0;

    double Bo0 = 2.0 * gc1 * (S[0][3] - S[1][3]);
    double Bo1 = 2.0 * gc2 * S[2][3];

    double Do0 = S[2][0] - S[2][1], Do1 = S[2][2];
    double Eo  = S[2][3];

    double T00 = 2.0 * gc1 * Ux00, T01 = 2.0 * gc1 * Ux01;
    double T10 = 2.0 * gc2 * Ux10, T11 = 2.0 * gc2 * Ux11;

    double d0 = (1.0 - p) * RG, d1v = p * RG;
    double M00 = d0 + Q00, M01 = Q01, M10 = Q10, M11 = d1v + Q11;
    double idet = 1.0 / (M00 * M11 - M01 * M10);
    double G00 =  M11 * idet, G01 = -M01 * idet;
    double G10 = -M10 * idet, G11 =  M00 * idet;

    double TG00 = T00 * G00 + T01 * G10, TG01 = T00 * G01 + T01 * G11;
    double TG10 = T10 * G00 + T11 * G10, TG11 = T10 * G01 + T11 * G11;

    double A00 = Ao00 - (TG00 * Ux00 + TG01 * Ux01);
    double A01 = Ao01 - (TG00 * Ux10 + TG01 * Ux11);
    double A10 = Ao10 - (TG10 * Ux00 + TG11 * Ux01);
    double A11 = Ao11 - (TG10 * Ux10 + TG11 * Ux11);

    double Bm0 = Bo0 - (TG00 * Uu0 + TG01 * Uu1);
    double Bm1 = Bo1 - (TG10 * Uu0 + TG11 * Uu1);

    double w0v = Uo0 * G00 + Uo1 * G10, w1v = Uo0 * G01 + Uo1 * G11;
    double Dm0 = Do0 - (w0v * Ux00 + w1v * Ux01);
    double Dm1 = Do1 - (w0v * Ux10 + w1v * Ux11);
    double Em  = Eo  - (w0v * Uu0 + w1v * Uu1);

    double den1 = -(A00 + A11);
    double den2 = A00 * A11 - A01 * A10;
    double Mm00 = A00 - Bm0 * Dm0, Mm01 = A01 - Bm0 * Dm1;
    double Mm10 = A10 - Bm1 * Dm0, Mm11 = A11 - Bm1 * Dm1;
    double num0 = Em;
    double num1 = -(Mm00 + Mm11) + (Em - 1.0) * den1;
    double num2 = (Mm00 * Mm11 - Mm01 * Mm10) + (Em - 1.0) * den2;

    coef[(size_t)b * 5 + 0] = num0;
    coef[(size_t)b * 5 + 1] = num1;
    coef[(size_t)b * 5 + 2] = num2;
    coef[(size_t)b * 5 + 3] = den1;
    coef[(size_t)b * 5 + 4] = den2;
}

// ---------------- radix-16 FFT machinery ----------------

static __device__ __forceinline__ float2 cmul(float2 a, float2 b) {
    return make_float2(a.x * b.x - a.y * b.y, a.x * b.y + a.y * b.x);
}
static __device__ __forceinline__ float2 cadd(float2 a, float2 b) { return make_float2(a.x + b.x, a.y + b.y); }
static __device__ __forceinline__ float2 csub(float2 a, float2 b) { return make_float2(a.x - b.x, a.y - b.y); }

static __device__ __forceinline__ int PAD(int i) { return i + (i >> 4); }

// In-register 16-point DFT. SGN=-1: forward (e^{-i}); SGN=+1: inverse (e^{+i}), unnormalized.
template <int SGN>
static __device__ __forceinline__ void dft16(float2 r[16]) {
    const float S = (float)SGN;
    float2 t[16];
#pragma unroll
    for (int n1 = 0; n1 < 4; ++n1) {
        float2 a = r[n1], b = r[n1 + 4], c = r[n1 + 8], d = r[n1 + 12];
        float2 A = cadd(a, c), B = cadd(b, d), C = csub(a, c), D = csub(b, d);
        float2 iD = make_float2(-S * D.y, S * D.x);
        t[n1 * 4 + 0] = cadd(A, B);
        t[n1 * 4 + 1] = cadd(C, iD);
        t[n1 * 4 + 2] = csub(A, B);
        t[n1 * 4 + 3] = csub(C, iD);
    }
    // W16^{S*n1*m2}, n1,m2 in 1..3 (k = n1*m2 <= 9)
    const float CC[10] = {1.f, 0.92387953251f, 0.70710678119f, 0.38268343236f, 0.f,
                          -0.38268343236f, -0.70710678119f, -0.92387953251f, -1.f, -0.92387953251f};
    const float SS[10] = {0.f, 0.38268343236f, 0.70710678119f, 0.92387953251f, 1.f,
                          0.92387953251f, 0.70710678119f, 0.38268343236f, 0.f, -0.38268343236f};
#pragma unroll
    for (int n1 = 1; n1 < 4; ++n1) {
#pragma unroll
        for (int m2 = 1; m2 < 4; ++m2) {
            const int k = n1 * m2;
            t[n1 * 4 + m2] = cmul(t[n1 * 4 + m2], make_float2(CC[k], S * SS[k]));
        }
    }
#pragma unroll
    for (int m2 = 0; m2 < 4; ++m2) {
        float2 a = t[m2], b = t[4 + m2], c = t[8 + m2], d = t[12 + m2];
        float2 A = cadd(a, c), B = cadd(b, d), C = csub(a, c), D = csub(b, d);
        float2 iD = make_float2(-S * D.y, S * D.x);
        r[m2]      = cadd(A, B);
        r[m2 + 4]  = cadd(C, iD);
        r[m2 + 8]  = csub(A, B);
        r[m2 + 12] = csub(C, iD);
    }
}

// apply r[m] *= w1^m, m=1..15
static __device__ __forceinline__ void twiddle_chain(float2 r[16], float2 w1) {
    float2 wa = w1;
    r[1] = cmul(r[1], wa);
#pragma unroll
    for (int m = 2; m < 16; ++m) {
        wa = cmul(wa, w1);
        r[m] = cmul(r[m], wa);
    }
}

__global__ __launch_bounds__(256)
void preamp_fft_kernel(const float* __restrict__ x,
                       const float* __restrict__ state,
                       const double* __restrict__ coef,
                       float* __restrict__ out) {
    __shared__ float2 a_s[NFFT + NFFT / 16];   // padded: 34 KB

    const int b = blockIdx.x;
    const int t = threadIdx.x;

    const float* st = state + (size_t)b * SSZ + (SSZ - LSEG);
    const float* xb = x + (size_t)b * LSEG;

    for (int i = t; i < NFFT; i += 256) {
        float v = (i < LSEG) ? st[i] : xb[i - LSEG];
        a_s[PAD(i)] = make_float2(v, 0.0f);
    }
    const double n0  = coef[(size_t)b * 5 + 0];
    const double n1c = coef[(size_t)b * 5 + 1];
    const double n2  = coef[(size_t)b * 5 + 2];
    const double dd1 = coef[(size_t)b * 5 + 3];
    const double dd2 = coef[(size_t)b * 5 + 4];
    __syncthreads();

    const float TW4096 = 0.00153398078788564f;  // 2*pi/4096
    const float TW256  = 0.02454369260617026f;  // 2*pi/256

    float2 r[16];

    // ---- forward pass A: span 256, twiddle W4096^{t*m} (after DFT) ----
#pragma unroll
    for (int m = 0; m < 16; ++m) r[m] = a_s[PAD(t + 256 * m)];
    dft16<-1>(r);
    {
        float sw, cw;
        __sincosf((float)t * TW4096, &sw, &cw);
        twiddle_chain(r, make_float2(cw, -sw));
    }
#pragma unroll
    for (int m = 0; m < 16; ++m) a_s[PAD(t + 256 * m)] = r[m];
    __syncthreads();

    // ---- forward pass B: span 16 within 256-blocks, twiddle W256^{j*m} ----
    {
        const int sub = t >> 4, j = t & 15;
        const int base = sub * 256 + j;
#pragma unroll
        for (int m = 0; m < 16; ++m) r[m] = a_s[PAD(base + 16 * m)];
        dft16<-1>(r);
        float sw, cw;
        __sincosf((float)j * TW256, &sw, &cw);
        twiddle_chain(r, make_float2(cw, -sw));
#pragma unroll
        for (int m = 0; m < 16; ++m) a_s[PAD(base + 16 * m)] = r[m];
    }
    __syncthreads();

    // ---- fused: forward span-1 + pointwise H (fp64) + inverse span-1 ----
    {
        const int base = 16 * t;
#pragma unroll
        for (int m = 0; m < 16; ++m) r[m] = a_s[PAD(base + m)];
        dft16<-1>(r);
        // position 16t+m holds X[k], k = (m<<8) | ((t&15)<<4) | (t>>4)
        const int klo = ((t & 15) << 4) | (t >> 4);
#pragma unroll
        for (int m = 0; m < 16; ++m) {
            const int k = (m << 8) | klo;
            float sw, cw;
            __sincosf((float)k * TW4096, &sw, &cw);
            const double zr = (double)cw, zi = -(double)sw;
            double ar = n0 * zr + n1c, ai = n0 * zi;
            double nr = ar * zr - ai * zi + n2, ni = ar * zi + ai * zr;
            double br = zr + dd1, bi = zi;
            double dr = br * zr - bi * zi + dd2, di = br * zi + bi * zr;
            double idn = 1.0 / (dr * dr + di * di);
            double hr = (nr * dr + ni * di) * idn;
            double hi = (ni * dr - nr * di) * idn;
            double Xr = (double)r[m].x, Xi = (double)r[m].y;
            r[m] = make_float2((float)(Xr * hr - Xi * hi), (float)(Xr * hi + Xi * hr));
        }
        dft16<1>(r);
#pragma unroll
        for (int m = 0; m < 16; ++m) a_s[PAD(base + m)] = r[m];
    }
    __syncthreads();

    // ---- inverse pass B: span 16, input twiddle W256^{-j*m} i.e. conj chain before DFT ----
    {
        const int sub = t >> 4, j = t & 15;
        const int base = sub * 256 + j;
#pragma unroll
        for (int m = 0; m < 16; ++m) r[m] = a_s[PAD(base + 16 * m)];
        float sw, cw;
        __sincosf((float)j * TW256, &sw, &cw);
        twiddle_chain(r, make_float2(cw, sw));   // e^{+i*2pi*j/256}
        dft16<1>(r);
#pragma unroll
        for (int m = 0; m < 16; ++m) a_s[PAD(base + 16 * m)] = r[m];
    }
    __syncthreads();

    // ---- inverse pass A: span 256, input twiddle W4096^{-t*m}; store tail directly ----
    {
#pragma unroll
        for (int m = 0; m < 16; ++m) r[m] = a_s[PAD(t + 256 * m)];
        float sw, cw;
        __sincosf((float)t * TW4096, &sw, &cw);
        twiddle_chain(r, make_float2(cw, sw));   // e^{+i*2pi*t/4096}
        dft16<1>(r);
        const float scale = 1.0f / (float)NFFT;
        float* ob = out + (size_t)b * LSEG;
#pragma unroll
        for (int m = 8; m < 16; ++m) {
            ob[t + 256 * (m - 8)] = r[m].x * scale;
        }
    }
}

extern "C" void kernel_launch(void* const* d_in, const int* in_sizes, int n_in,
                              void* d_out, int out_size, void* d_ws, size_t ws_size,
                              hipStream_t stream) {
    const float* x     = (const float*)d_in[0];
    const float* cond  = (const float*)d_in[1];
    const float* state = (const float*)d_in[2];
    const float* a_rg  = (const float*)d_in[3];
    const float* a_r1  = (const float*)d_in[4];
    const float* a_c1  = (const float*)d_in[5];
    const float* a_c2  = (const float*)d_in[6];
    const float* c_w   = (const float*)d_in[7];
    const float* c_b   = (const float*)d_in[8];
    float* out = (float*)d_out;

    const int B = in_sizes[1];          // cond is [B,1]
    double* coef = (double*)d_ws;       // B*5 doubles

    preamp_coef_kernel<<<dim3((B + 255) / 256), dim3(256), 0, stream>>>(
        cond, a_rg, a_r1, a_c1, a_c2, c_w, c_b, coef, B);
    preamp_fft_kernel<<<dim3(B), dim3(256), 0, stream>>>(x, state, coef, out);
}